// Round 7
// baseline (120.489 us; speedup 1.0000x reference)
//
#include <hip/hip_runtime.h>

// Problem constants: B=2, L=2048, H=8, D=64, window=32, stride=64
#define Bc 2
#define Lc 2048
#define Hc 8
#define Dc 64
#define TL 16                 // rows per block
#define NT (Lc / TL)          // 128 tiles
#define RHD (Hc * Dc)         // 512 floats between consecutive s rows
#define SP1 65                // stride+1
#define SCALE_LOG2E 0.1803368801111244f   // (1/8) * log2(e); use exp2f

// DPP-based add of a permuted copy: pure VALU, no DS traffic.
// PROVEN on gfx950 (R3-R5). Full masks + bound_ctrl only; row_bcast15/31
// with partial row_mask FAILED correctness on gfx950 (R6) — do not use.
template <int CTRL>
__device__ __forceinline__ float dpp_add(float x) {
    int p = __builtin_amdgcn_update_dpp(0, __float_as_int(x), CTRL, 0xF, 0xF, true);
    return x + __int_as_float(p);
}
// 16-lane-row sum (verified R3-R5): xor1, xor2, half-mirror, mirror.
__device__ __forceinline__ float row16_sum(float x) {
    x = dpp_add<0xB1>(x);
    x = dpp_add<0x4E>(x);
    x = dpp_add<0x141>(x);
    x = dpp_add<0x140>(x);
    return x;
}

// ---------------------------------------------------------------------------
// Kernel 1: per-(b,h) tile sums of V -> partials[bh][t][d]
// ---------------------------------------------------------------------------
__global__ __launch_bounds__(256)
void dozer_chunk_sum(const float* __restrict__ V, float* __restrict__ partials) {
    const int bh = blockIdx.x;
    const int t  = blockIdx.y;
    const int b  = bh >> 3;
    const int h  = bh & 7;
    const int g  = threadIdx.x >> 6;
    const int d  = threadIdx.x & 63;
    const float* Vbh = V + (size_t)b * Lc * RHD + h * Dc;
    const int l0 = t * TL;
    float s = 0.f;
    for (int r = g; r < TL; r += 4)
        s += Vbh[(size_t)(l0 + r) * RHD + d];
    __shared__ float red[4][64];
    red[g][d] = s;
    __syncthreads();
    if (g == 0)
        partials[((size_t)bh * NT + t) * 64 + d] =
            red[0][d] + red[1][d] + red[2][d] + red[3][d];
}

// ---------------------------------------------------------------------------
// Kernel 2: main kernel. Block = (bh, tile of 16 rows), 4 waves, 4 rows/wave
// processed as 2 concurrent row-PAIRS (ILP). Lane layout: p = lane>>4 (slot),
// dd = lane&15 (d-quad). Band offsets 0..16 from LDS; far offsets 65f from
// global, depth-1 prefetch with 4 loads in flight. Cross-group combine via
// __shfl_xor 16/32 (proven R5); writer group p==0.
// ---------------------------------------------------------------------------
__global__ __launch_bounds__(256)
void dozer_main(const float* __restrict__ Q, const float* __restrict__ K,
                const float* __restrict__ V, const float* __restrict__ partials,
                float* __restrict__ out) {
    const int bh   = blockIdx.x;
    const int t    = (NT - 1) - blockIdx.y;   // heavy tiles first
    const int b    = bh >> 3;
    const int h    = bh & 7;
    const int tid  = threadIdx.x;
    const int wave = tid >> 6;
    const int lane = tid & 63;
    const int l0   = t * TL;

    const float* Qbh = Q + (size_t)b * Lc * RHD + h * Dc;
    const float* Kbh = K + (size_t)b * Lc * RHD + h * Dc;
    const float* Vbh = V + (size_t)b * Lc * RHD + h * Dc;

    __shared__ float Kband[32][64];
    __shared__ float Vband[32][64];
    __shared__ float Ptile[TL][64];
    // red aliases Kband's first 2 KB: consumed before staging overwrites it.
    float (*red)[64] = (float(*)[64])Kband;

    // ---- prefix phase: wave w owns rows 4w..4w+3 ----
    {
        const int d = lane;
        float pbase = 0.f;
        if (partials) {
            const float* pb = partials + (size_t)bh * NT * 64;
            #pragma unroll 4
            for (int c = wave; c < t; c += 4)
                pbase += pb[(size_t)c * 64 + d];
        } else {
            for (int s = wave; s < l0; s += 4)
                pbase += Vbh[(size_t)s * RHD + d];
        }
        const float* vr = Vbh + (size_t)(l0 + 4 * wave) * RHD + d;
        const float x0 = vr[0];
        const float x1 = vr[RHD];
        const float x2 = vr[2 * RHD];
        const float x3 = vr[3 * RHD];
        const float s0 = x0, s1 = s0 + x1, s2 = s1 + x2, s3 = s2 + x3;
        red[wave][d]     = pbase;
        red[4 + wave][d] = s3;
        __syncthreads();
        float base = red[0][d] + red[1][d] + red[2][d] + red[3][d];
        if (wave > 0) base += red[4][d];
        if (wave > 1) base += red[5][d];
        if (wave > 2) base += red[6][d];
        Ptile[4 * wave + 0][d] = base + s0;
        Ptile[4 * wave + 1][d] = base + s1;
        Ptile[4 * wave + 2][d] = base + s2;
        Ptile[4 * wave + 3][d] = base + s3;
        __syncthreads();
    }

    // ---- stage band rows [l0-16, l0+15] of K and V into LDS ----
    {
        const int i  = tid >> 4;            // 0..15
        const int c4 = (tid & 15) * 4;
        #pragma unroll
        for (int rnd = 0; rnd < 2; ++rnd) {
            const int ii = i + 16 * rnd;    // 0..31
            int j = l0 - 16 + ii; if (j < 0) j = 0;   // t=0 garbage masked later
            *(float4*)&Kband[ii][c4] = *(const float4*)(Kbh + (size_t)j * RHD + c4);
            *(float4*)&Vband[ii][c4] = *(const float4*)(Vbh + (size_t)j * RHD + c4);
        }
        __syncthreads();
    }

    const int p  = lane >> 4;
    const int dd = lane & 15;

    for (int rp = 0; rp < 2; ++rp) {
        const int rA = wave * 4 + rp * 2;
        const int rB = rA + 1;
        const int lA = l0 + rA;
        const int lB = lA + 1;
        const int nkA = lA / SP1;           // far offsets 65f, f = 1..nk
        const int nkB = lB / SP1;           // nkB >= nkA
        const int nfar = (nkB + 3) >> 2;

        float4 qa = *(const float4*)&Qbh[(size_t)lA * RHD + dd * 4];
        float4 qb = *(const float4*)&Qbh[(size_t)lB * RHD + dd * 4];
        qa.x *= SCALE_LOG2E; qa.y *= SCALE_LOG2E; qa.z *= SCALE_LOG2E; qa.w *= SCALE_LOG2E;
        qb.x *= SCALE_LOG2E; qb.y *= SCALE_LOG2E; qb.z *= SCALE_LOG2E; qb.w *= SCALE_LOG2E;

        float4 accA = make_float4(0.f, 0.f, 0.f, 0.f);
        float4 accB = accA;
        float  denA = 0.f, denB = 0.f;

        auto farj = [&](int l, int m) {
            int j = l - SP1 * (1 + p + 4 * m);
            return j < 0 ? 0 : j;
        };
        auto step = [&](const float4& q4, const float4& k4, const float4& v4,
                        bool ok, float4& acc, float& den) {
            float dot = q4.x * k4.x + q4.y * k4.y + q4.z * k4.z + q4.w * k4.w;
            dot = row16_sum(dot);
            float w = exp2f(dot) - 1.f;
            w = ok ? w : 0.f;
            acc.x += w * v4.x; acc.y += w * v4.y;
            acc.z += w * v4.z; acc.w += w * v4.w;
            den += w;
        };

        // far prologue: issue global loads now; band compute covers latency
        float4 kA = make_float4(0.f,0.f,0.f,0.f), vA = kA, kB = kA, vB = kA;
        float4 kA2 = kA, vA2 = kA, kB2 = kA, vB2 = kA;
        if (nfar > 0) {
            const int jA = farj(lA, 0), jB = farj(lB, 0);
            kA = *(const float4*)(Kbh + (size_t)jA * RHD + dd * 4);
            vA = *(const float4*)(Vbh + (size_t)jA * RHD + dd * 4);
            kB = *(const float4*)(Kbh + (size_t)jB * RHD + dd * 4);
            vB = *(const float4*)(Vbh + (size_t)jB * RHD + dd * 4);
        }

        // ---- band from LDS: offsets 0..15, two rows interleaved ----
        #pragma unroll
        for (int it = 0; it < 4; ++it) {
            const int off  = p + 4 * it;
            const int idxA = rA + 16 - off;        // [2,30]; idxB = idxA+1 in [3,31]
            step(qa, *(const float4*)&Kband[idxA][dd * 4],
                     *(const float4*)&Vband[idxA][dd * 4], off <= lA, accA, denA);
            step(qb, *(const float4*)&Kband[idxA + 1][dd * 4],
                     *(const float4*)&Vband[idxA + 1][dd * 4], off <= lB, accB, denB);
        }
        {   // band edge offset 16 (slot group p==0), idx = r
            step(qa, *(const float4*)&Kband[rA][dd * 4],
                     *(const float4*)&Vband[rA][dd * 4],
                 (p == 0) && (lA >= 16), accA, denA);
            step(qb, *(const float4*)&Kband[rB][dd * 4],
                     *(const float4*)&Vband[rB][dd * 4],
                 (p == 0) && (lB >= 16), accB, denB);
        }

        // ---- far loop: depth-1 prefetch, 2-row ILP (4 loads in flight) ----
        for (int m = 0; m < nfar; ++m) {
            if (m + 1 < nfar) {
                const int jA = farj(lA, m + 1), jB = farj(lB, m + 1);
                kA2 = *(const float4*)(Kbh + (size_t)jA * RHD + dd * 4);
                vA2 = *(const float4*)(Vbh + (size_t)jA * RHD + dd * 4);
                kB2 = *(const float4*)(Kbh + (size_t)jB * RHD + dd * 4);
                vB2 = *(const float4*)(Vbh + (size_t)jB * RHD + dd * 4);
            }
            const int f = 1 + p + 4 * m;
            step(qa, kA, vA, f <= nkA, accA, denA);
            step(qb, kB, vB, f <= nkB, accB, denB);
            kA = kA2; vA = vA2; kB = kB2; vB = vB2;
        }

        // ---- combine across the 4 position groups (xor 16, 32) — proven R5 ----
        accA.x += __shfl_xor(accA.x, 16, 64); accA.x += __shfl_xor(accA.x, 32, 64);
        accA.y += __shfl_xor(accA.y, 16, 64); accA.y += __shfl_xor(accA.y, 32, 64);
        accA.z += __shfl_xor(accA.z, 16, 64); accA.z += __shfl_xor(accA.z, 32, 64);
        accA.w += __shfl_xor(accA.w, 16, 64); accA.w += __shfl_xor(accA.w, 32, 64);
        denA   += __shfl_xor(denA, 16, 64);   denA   += __shfl_xor(denA, 32, 64);
        accB.x += __shfl_xor(accB.x, 16, 64); accB.x += __shfl_xor(accB.x, 32, 64);
        accB.y += __shfl_xor(accB.y, 16, 64); accB.y += __shfl_xor(accB.y, 32, 64);
        accB.z += __shfl_xor(accB.z, 16, 64); accB.z += __shfl_xor(accB.z, 32, 64);
        accB.w += __shfl_xor(accB.w, 16, 64); accB.w += __shfl_xor(accB.w, 32, 64);
        denB   += __shfl_xor(denB, 16, 64);   denB   += __shfl_xor(denB, 32, 64);

        const float invA = 1.f / ((float)(lA + 1) + denA);
        const float invB = 1.f / ((float)(lB + 1) + denB);
        if (p == 0) {
            const float4 PA = *(const float4*)&Ptile[rA][dd * 4];
            const float4 PB = *(const float4*)&Ptile[rB][dd * 4];
            float4 oA, oB;
            oA.x = (PA.x + accA.x) * invA; oA.y = (PA.y + accA.y) * invA;
            oA.z = (PA.z + accA.z) * invA; oA.w = (PA.w + accA.w) * invA;
            oB.x = (PB.x + accB.x) * invB; oB.y = (PB.y + accB.y) * invB;
            oB.z = (PB.z + accB.z) * invB; oB.w = (PB.w + accB.w) * invB;
            *(float4*)&out[((size_t)(b * Lc + lA) * Hc + h) * Dc + dd * 4] = oA;
            *(float4*)&out[((size_t)(b * Lc + lB) * Hc + h) * Dc + dd * 4] = oB;
        }
    }
}

// ---------------------------------------------------------------------------
extern "C" void kernel_launch(void* const* d_in, const int* in_sizes, int n_in,
                              void* d_out, int out_size, void* d_ws, size_t ws_size,
                              hipStream_t stream) {
    // inputs: 0=x (unused), 1=queries, 2=keys, 3=values, 4=attn_mask (analytic)
    const float* Q = (const float*)d_in[1];
    const float* K = (const float*)d_in[2];
    const float* V = (const float*)d_in[3];
    float* out = (float*)d_out;

    const size_t need = (size_t)Bc * Hc * NT * 64 * sizeof(float);  // 512 KB
    float* partials = (ws_size >= need) ? (float*)d_ws : nullptr;

    dim3 grid(Bc * Hc, NT);   // bh fastest: balances per-CU tile mix
    if (partials)
        dozer_chunk_sum<<<grid, 256, 0, stream>>>(V, partials);
    dozer_main<<<grid, 256, 0, stream>>>(Q, K, V, partials, out);
}